// Round 1
// baseline (343.211 us; speedup 1.0000x reference)
//
#include <hip/hip_runtime.h>

// MSDeformAttn: B=2, LQ=LV=11109, D=256, NH=8, HD=32, NL=3, NP=4
// shapes: (92,92),(46,46),(23,23); starts: 0, 8464, 10580
#define LQn   11109
#define Bn    2
#define MTOT  (Bn * LQn)   // 22218
#define NHh   8
#define HDc   32

typedef __attribute__((ext_vector_type(8))) short short8;
typedef __attribute__((ext_vector_type(4))) float f32x4;

__device__ __forceinline__ unsigned short f2bf(float f) {
  union { float f; unsigned int u; } v; v.f = f;
  unsigned int r = v.u + 0x7fffu + ((v.u >> 16) & 1u);  // RNE
  return (unsigned short)(r >> 16);
}

// ---------------- elementwise fp32 -> bf16 cast (vec4) ----------------
__global__ __launch_bounds__(256) void cast4_kernel(const float* __restrict__ src,
                                                    unsigned short* __restrict__ dst,
                                                    int n4) {
  int i = blockIdx.x * 256 + threadIdx.x;
  if (i >= n4) return;
  float4 v = ((const float4*)src)[i];
  ushort4 o;
  o.x = f2bf(v.x); o.y = f2bf(v.y); o.z = f2bf(v.z); o.w = f2bf(v.w);
  ((ushort4*)dst)[i] = o;
}

// ---------------- weight prep: transpose to (N x K) bf16, concat biases ----------------
__global__ __launch_bounds__(256) void prep_weights(
    const float* __restrict__ Wval, const float* __restrict__ Woff,
    const float* __restrict__ Wattn, const float* __restrict__ Wout,
    const float* __restrict__ boff, const float* __restrict__ battn,
    unsigned short* __restrict__ Wval_t, unsigned short* __restrict__ Wcat_t,
    unsigned short* __restrict__ Wout_t, float* __restrict__ bcat) {
  int i = blockIdx.x * 256 + threadIdx.x;   // grid = 288 blocks -> i < 73728
  int n = i >> 8, k = i & 255;              // Wt[n][k] = W[k][n]
  if (n < 256) {
    Wval_t[i] = f2bf(Wval[k * 256 + n]);
    Wout_t[i] = f2bf(Wout[k * 256 + n]);
  }
  float src = (n < 192) ? Woff[k * 192 + n] : Wattn[k * 96 + (n - 192)];
  Wcat_t[i] = f2bf(src);
  if (i < 288) bcat[i] = (i < 192) ? boff[i] : battn[i - 192];
}

// ---------------- bf16 MFMA GEMM: C[M,N] = A[M,256] * Bt[N,256]^T + bias ----------------
// block = 256 threads (4 waves, 2x2), tile 64x64, BK=32, K fixed = 256
__global__ __launch_bounds__(256) void gemm_bf16_64x64(
    const unsigned short* __restrict__ A,   // M x 256 row-major bf16
    const unsigned short* __restrict__ Bt,  // N x 256 row-major bf16 (already transposed)
    const float* __restrict__ bias,         // N fp32
    float* __restrict__ C,                  // M x N fp32
    int M, int N) {
  __shared__ unsigned short As[64][40];  // +8 pad: 80B row stride (16B-aligned, 2-way banks)
  __shared__ unsigned short Bs[64][40];

  const int t = threadIdx.x;
  const int bm = blockIdx.x, bn = blockIdx.y;
  const int wave = t >> 6, lane = t & 63;
  const int wm = wave >> 1, wn = wave & 1;
  const int quad = lane >> 4, l16 = lane & 15;

  const int ldr = t >> 2;          // 0..63 row within tile
  const int ldk = (t & 3) * 8;     // 0/8/16/24 k-offset
  const int arow = bm * 64 + ldr;
  const int brow = bn * 64 + ldr;

  f32x4 acc[2][2];
  for (int i = 0; i < 2; i++)
    for (int j = 0; j < 2; j++) acc[i][j] = (f32x4){0.f, 0.f, 0.f, 0.f};

  for (int kb = 0; kb < 8; kb++) {
    const int k0 = kb * 32;
    uint4 av = {0u, 0u, 0u, 0u}, bv = {0u, 0u, 0u, 0u};
    if (arow < M) av = *(const uint4*)(A + (size_t)arow * 256 + k0 + ldk);
    if (brow < N) bv = *(const uint4*)(Bt + (size_t)brow * 256 + k0 + ldk);
    __syncthreads();                       // protect previous iter's LDS reads
    *(uint4*)(&As[ldr][ldk]) = av;
    *(uint4*)(&Bs[ldr][ldk]) = bv;
    __syncthreads();
    short8 af[2], bfr[2];
    for (int i = 0; i < 2; i++)
      af[i] = *(const short8*)(&As[wm * 32 + i * 16 + l16][quad * 8]);
    for (int j = 0; j < 2; j++)
      bfr[j] = *(const short8*)(&Bs[wn * 32 + j * 16 + l16][quad * 8]);
    for (int i = 0; i < 2; i++)
      for (int j = 0; j < 2; j++)
        acc[i][j] = __builtin_amdgcn_mfma_f32_16x16x32_bf16(af[i], bfr[j], acc[i][j], 0, 0, 0);
  }

  // D: col = lane&15, row = quad*4 + reg
  for (int i = 0; i < 2; i++)
    for (int j = 0; j < 2; j++) {
      int colg = bn * 64 + wn * 32 + j * 16 + l16;
      if (colg >= N) continue;
      float bsv = bias[colg];
      int row0 = bm * 64 + wm * 32 + i * 16 + quad * 4;
      for (int r = 0; r < 4; r++) {
        int rg = row0 + r;
        if (rg < M) C[(size_t)rg * N + colg] = acc[i][j][r] + bsv;
      }
    }
}

// ---------------- sampling + softmax + weighted sum ----------------
// block per (b,q); thread = (h = t>>5, c = t&31)
__global__ __launch_bounds__(256) void msda_sample(
    const float* __restrict__ value,    // (B*LV, 256) fp32, (b,pix) rows, inner h*32+c
    const float* __restrict__ logits,   // (M, 288): 192 offset logits + 96 attn logits
    const float* __restrict__ refp,     // (B, LQ, 3, 2) fp32 (y,x)
    unsigned short* __restrict__ sampled) {  // bf16 (M, 256)
  const int bq = blockIdx.x;
  const int b = bq / LQn;
  const int t = threadIdx.x;
  const int h = t >> 5, c = t & 31;

  __shared__ float lg[288];
  __shared__ float rf[6];
  for (int i = t; i < 288; i += 256) lg[i] = logits[(size_t)bq * 288 + i];
  if (t < 6) rf[t] = refp[(size_t)bq * 6 + t];
  __syncthreads();

  // softmax over the 12 attn logits of head h (broadcast LDS reads)
  float mx = -1e30f;
#pragma unroll
  for (int i = 0; i < 12; i++) mx = fmaxf(mx, lg[192 + h * 12 + i]);
  float den = 0.f;
#pragma unroll
  for (int i = 0; i < 12; i++) den += __expf(lg[192 + h * 12 + i] - mx);
  const float rden = 1.0f / den;

  const int Hs[3] = {92, 46, 23};
  const int Ss[3] = {0, 8464, 10580};
  const float* vb = value + (size_t)b * LQn * 256;  // LV == LQ
  float acc = 0.f;
#pragma unroll
  for (int l = 0; l < 3; l++) {
    const int Hl = Hs[l], Wl = Hs[l];  // square levels
    const int S = Ss[l];
    const float ry = rf[l * 2 + 0], rx = rf[l * 2 + 1];
#pragma unroll
    for (int p = 0; p < 4; p++) {
      const int ob = (h * 3 + l) * 4 + p;       // == h*12 + l*4 + p
      const float offy = lg[2 * ob], offx = lg[2 * ob + 1];
      const float aw = __expf(lg[192 + ob] - mx) * rden;
      // x = ref_x*W + off_x - 0.5 ; y = ref_y*H + off_y - 0.5 (align_corners=False)
      const float x = rx * Wl + offx - 0.5f;
      const float y = ry * Hl + offy - 0.5f;
      const float xf = floorf(x), yf = floorf(y);
      const int x0 = (int)xf, y0 = (int)yf;
      const float lx = x - xf, ly = y - yf;
      const float w00 = (1.f - ly) * (1.f - lx), w01 = (1.f - ly) * lx;
      const float w10 = ly * (1.f - lx), w11 = ly * lx;
      const bool xv0 = (x0 >= 0) & (x0 < Wl), xv1 = (x0 + 1 >= 0) & (x0 + 1 < Wl);
      const bool yv0 = (y0 >= 0) & (y0 < Hl), yv1 = (y0 + 1 >= 0) & (y0 + 1 < Hl);
      float s = 0.f;
      if (yv0 & xv0) s += w00 * vb[((size_t)(S + y0 * Wl + x0) * 8 + h) * 32 + c];
      if (yv0 & xv1) s += w01 * vb[((size_t)(S + y0 * Wl + x0 + 1) * 8 + h) * 32 + c];
      if (yv1 & xv0) s += w10 * vb[((size_t)(S + (y0 + 1) * Wl + x0) * 8 + h) * 32 + c];
      if (yv1 & xv1) s += w11 * vb[((size_t)(S + (y0 + 1) * Wl + x0 + 1) * 8 + h) * 32 + c];
      acc += aw * s;
    }
  }
  sampled[(size_t)bq * 256 + t] = f2bf(acc);
}

// ---------------- host launch ----------------
extern "C" void kernel_launch(void* const* d_in, const int* in_sizes, int n_in,
                              void* d_out, int out_size, void* d_ws, size_t ws_size,
                              hipStream_t stream) {
  const float* query      = (const float*)d_in[0];
  const float* refp       = (const float*)d_in[1];
  const float* value_flat = (const float*)d_in[2];
  const float* W_val      = (const float*)d_in[3];
  const float* b_val      = (const float*)d_in[4];
  const float* W_off      = (const float*)d_in[5];
  const float* b_off      = (const float*)d_in[6];
  const float* W_attn     = (const float*)d_in[7];
  const float* b_attn     = (const float*)d_in[8];
  const float* W_out      = (const float*)d_in[9];
  const float* b_out      = (const float*)d_in[10];

  char* w = (char*)d_ws;
  size_t o = 0;
  auto carve = [&](size_t bytes) -> void* {
    void* p = (void*)(w + o);
    o += (bytes + 255) & ~(size_t)255;
    return p;
  };
  unsigned short* q_bf    = (unsigned short*)carve((size_t)MTOT * 256 * 2);
  unsigned short* v_bf    = (unsigned short*)carve((size_t)MTOT * 256 * 2);
  unsigned short* Wval_t  = (unsigned short*)carve(256 * 256 * 2);
  unsigned short* Wcat_t  = (unsigned short*)carve(288 * 256 * 2);
  unsigned short* Wout_t  = (unsigned short*)carve(256 * 256 * 2);
  float*          bcat    = (float*)carve(288 * 4);
  float*          value_f = (float*)carve((size_t)MTOT * 256 * 4);
  float*          logits  = (float*)carve((size_t)MTOT * 288 * 4);
  unsigned short* samp_bf = (unsigned short*)carve((size_t)MTOT * 256 * 2);

  const int n4 = MTOT * 256 / 4;                 // 1,421,952
  const int cgrid = (n4 + 255) / 256;            // 5555
  cast4_kernel<<<cgrid, 256, 0, stream>>>(query, q_bf, n4);
  cast4_kernel<<<cgrid, 256, 0, stream>>>(value_flat, v_bf, n4);
  prep_weights<<<288, 256, 0, stream>>>(W_val, W_off, W_attn, W_out, b_off, b_attn,
                                        Wval_t, Wcat_t, Wout_t, bcat);

  const int mg = (MTOT + 63) / 64;               // 348
  dim3 g1(mg, 4);                                // N=256
  gemm_bf16_64x64<<<g1, 256, 0, stream>>>(v_bf, Wval_t, b_val, value_f, MTOT, 256);
  dim3 g2(mg, 5);                                // N=288
  gemm_bf16_64x64<<<g2, 256, 0, stream>>>(q_bf, Wcat_t, bcat, logits, MTOT, 288);

  msda_sample<<<MTOT, 256, 0, stream>>>(value_f, logits, refp, samp_bf);

  dim3 g3(mg, 4);
  gemm_bf16_64x64<<<g3, 256, 0, stream>>>(samp_bf, Wout_t, b_out, (float*)d_out, MTOT, 256);
}

// Round 2
// 201.571 us; speedup vs baseline: 1.7027x; 1.7027x over previous
//
#include <hip/hip_runtime.h>

// MSDeformAttn: B=2, LQ=LV=11109, D=256, NH=8, HD=32, NL=3, NP=4
// shapes: (92,92),(46,46),(23,23); starts: 0, 8464, 10580
#define LQn   11109
#define Bn    2
#define MTOT  (Bn * LQn)   // 22218

typedef __attribute__((ext_vector_type(8))) short short8;
typedef __attribute__((ext_vector_type(4))) float f32x4;

__device__ __forceinline__ unsigned short f2bf(float f) {
  union { float f; unsigned int u; } v; v.f = f;
  unsigned int r = v.u + 0x7fffu + ((v.u >> 16) & 1u);  // RNE
  return (unsigned short)(r >> 16);
}
__device__ __forceinline__ float bf2f(unsigned short u) {
  union { unsigned int u; float f; } v; v.u = ((unsigned int)u) << 16;
  return v.f;
}

// ---------------- elementwise fp32 -> bf16 cast (vec4) ----------------
__global__ __launch_bounds__(256) void cast4_kernel(const float* __restrict__ src,
                                                    unsigned short* __restrict__ dst,
                                                    int n4) {
  int i = blockIdx.x * 256 + threadIdx.x;
  if (i >= n4) return;
  float4 v = ((const float4*)src)[i];
  ushort4 o;
  o.x = f2bf(v.x); o.y = f2bf(v.y); o.z = f2bf(v.z); o.w = f2bf(v.w);
  ((ushort4*)dst)[i] = o;
}

// ---------------- weight prep: transpose to (N x K) bf16, concat biases ----------------
__global__ __launch_bounds__(256) void prep_weights(
    const float* __restrict__ Wval, const float* __restrict__ Woff,
    const float* __restrict__ Wattn, const float* __restrict__ Wout,
    const float* __restrict__ boff, const float* __restrict__ battn,
    unsigned short* __restrict__ Wval_t, unsigned short* __restrict__ Wcat_t,
    unsigned short* __restrict__ Wout_t, float* __restrict__ bcat) {
  int i = blockIdx.x * 256 + threadIdx.x;   // grid = 288 blocks -> i < 73728
  int n = i >> 8, k = i & 255;              // Wt[n][k] = W[k][n]
  if (n < 256) {
    Wval_t[i] = f2bf(Wval[k * 256 + n]);
    Wout_t[i] = f2bf(Wout[k * 256 + n]);
  }
  float src = (n < 192) ? Woff[k * 192 + n] : Wattn[k * 96 + (n - 192)];
  Wcat_t[i] = f2bf(src);
  if (i < 288) bcat[i] = (i < 192) ? boff[i] : battn[i - 192];
}

// ---------------- bf16 MFMA GEMM: C[M,N] = A[M,256] * Bt[N,256]^T + bias ----------------
// block = 256 threads (4 waves, 2x2), tile 64x64, BK=32, K fixed = 256
template <bool BF16OUT>
__global__ __launch_bounds__(256) void gemm_bf16_64x64(
    const unsigned short* __restrict__ A,   // M x 256 row-major bf16
    const unsigned short* __restrict__ Bt,  // N x 256 row-major bf16 (transposed)
    const float* __restrict__ bias,         // N fp32
    void* __restrict__ Cout,                // M x N fp32 or bf16
    int M, int N) {
  __shared__ unsigned short As[64][40];
  __shared__ unsigned short Bs[64][40];

  const int t = threadIdx.x;
  const int bm = blockIdx.x, bn = blockIdx.y;
  const int wave = t >> 6, lane = t & 63;
  const int wm = wave >> 1, wn = wave & 1;
  const int quad = lane >> 4, l16 = lane & 15;

  const int ldr = t >> 2;
  const int ldk = (t & 3) * 8;
  const int arow = bm * 64 + ldr;
  const int brow = bn * 64 + ldr;

  f32x4 acc[2][2];
  for (int i = 0; i < 2; i++)
    for (int j = 0; j < 2; j++) acc[i][j] = (f32x4){0.f, 0.f, 0.f, 0.f};

  for (int kb = 0; kb < 8; kb++) {
    const int k0 = kb * 32;
    uint4 av = {0u, 0u, 0u, 0u}, bv = {0u, 0u, 0u, 0u};
    if (arow < M) av = *(const uint4*)(A + (size_t)arow * 256 + k0 + ldk);
    if (brow < N) bv = *(const uint4*)(Bt + (size_t)brow * 256 + k0 + ldk);
    __syncthreads();
    *(uint4*)(&As[ldr][ldk]) = av;
    *(uint4*)(&Bs[ldr][ldk]) = bv;
    __syncthreads();
    short8 af[2], bfr[2];
    for (int i = 0; i < 2; i++)
      af[i] = *(const short8*)(&As[wm * 32 + i * 16 + l16][quad * 8]);
    for (int j = 0; j < 2; j++)
      bfr[j] = *(const short8*)(&Bs[wn * 32 + j * 16 + l16][quad * 8]);
    for (int i = 0; i < 2; i++)
      for (int j = 0; j < 2; j++)
        acc[i][j] = __builtin_amdgcn_mfma_f32_16x16x32_bf16(af[i], bfr[j], acc[i][j], 0, 0, 0);
  }

  for (int i = 0; i < 2; i++)
    for (int j = 0; j < 2; j++) {
      int colg = bn * 64 + wn * 32 + j * 16 + l16;
      if (colg >= N) continue;
      float bsv = bias[colg];
      int row0 = bm * 64 + wm * 32 + i * 16 + quad * 4;
      for (int r = 0; r < 4; r++) {
        int rg = row0 + r;
        if (rg < M) {
          float v = acc[i][j][r] + bsv;
          if (BF16OUT) ((unsigned short*)Cout)[(size_t)rg * N + colg] = f2bf(v);
          else         ((float*)Cout)[(size_t)rg * N + colg] = v;
        }
      }
    }
}

// ---------------- sampling + softmax + weighted sum, v2 ----------------
// 1 wave per query, 4 queries per 256-block. Phase 1: 96 (h,p) slots build
// premultiplied corner weights + clamped indices in LDS. Phase 2: lane =
// (h = lane>>3, cg = lane&7) gathers ushort4 (4 channels) per corner.
__global__ __launch_bounds__(256) void msda_sample2(
    const unsigned short* __restrict__ value,   // (M,256) bf16
    const float* __restrict__ logits,           // (M,288)
    const float* __restrict__ refp,             // (M,3,2) (y,x)
    unsigned short* __restrict__ sampled) {     // (M,256) bf16
  __shared__ float lg[4][288];
  __shared__ float rfs[4][6];
  __shared__ float tw[4][96][4];
  __shared__ int   ti[4][96][4];

  const int t = threadIdx.x;
  const int ql = t >> 6;
  const int lane = t & 63;
  const int bq = blockIdx.x * 4 + ql;
  const bool qvalid = bq < MTOT;

  if (qvalid) {
    for (int i = lane; i < 288; i += 64) lg[ql][i] = logits[(size_t)bq * 288 + i];
    if (lane < 6) rfs[ql][lane] = refp[(size_t)bq * 6 + lane];
  }
  __syncthreads();

  if (qvalid) {
    const int Hs[3] = {92, 46, 23};
    const int Ss[3] = {0, 8464, 10580};
    for (int s = lane; s < 96; s += 64) {
      const int h = s / 12;
      const int pl = s - h * 12;
      const int l = pl >> 2;
      const int H = Hs[l], W = Hs[l], S = Ss[l];
      float mx = -1e30f;
#pragma unroll
      for (int i = 0; i < 12; i++) mx = fmaxf(mx, lg[ql][192 + h * 12 + i]);
      float den = 0.f;
#pragma unroll
      for (int i = 0; i < 12; i++) den += __expf(lg[ql][192 + h * 12 + i] - mx);
      const float aw = __expf(lg[ql][192 + s] - mx) / den;

      const float offy = lg[ql][2 * s], offx = lg[ql][2 * s + 1];
      const float x = rfs[ql][l * 2 + 1] * W + offx - 0.5f;
      const float y = rfs[ql][l * 2 + 0] * H + offy - 0.5f;
      const float xf = floorf(x), yf = floorf(y);
      const int x0 = (int)xf, y0 = (int)yf;
      const float lx = x - xf, ly = y - yf;
      const bool xv0 = (x0 >= 0) & (x0 < W), xv1 = (x0 + 1 >= 0) & (x0 + 1 < W);
      const bool yv0 = (y0 >= 0) & (y0 < H), yv1 = (y0 + 1 >= 0) & (y0 + 1 < H);
      const int xc0 = min(max(x0, 0), W - 1), xc1 = min(max(x0 + 1, 0), W - 1);
      const int yc0 = min(max(y0, 0), H - 1), yc1 = min(max(y0 + 1, 0), H - 1);
      ti[ql][s][0] = S + yc0 * W + xc0;
      ti[ql][s][1] = S + yc0 * W + xc1;
      ti[ql][s][2] = S + yc1 * W + xc0;
      ti[ql][s][3] = S + yc1 * W + xc1;
      tw[ql][s][0] = (yv0 & xv0) ? aw * (1.f - ly) * (1.f - lx) : 0.f;
      tw[ql][s][1] = (yv0 & xv1) ? aw * (1.f - ly) * lx : 0.f;
      tw[ql][s][2] = (yv1 & xv0) ? aw * ly * (1.f - lx) : 0.f;
      tw[ql][s][3] = (yv1 & xv1) ? aw * ly * lx : 0.f;
    }
  }
  __syncthreads();

  if (qvalid) {
    const int h = lane >> 3, cg = lane & 7;
    const int coff = h * 32 + cg * 4;
    const unsigned short* vb = value + (size_t)(bq / LQn) * LQn * 256 + coff;
    float a0 = 0.f, a1 = 0.f, a2 = 0.f, a3 = 0.f;
#pragma unroll
    for (int p = 0; p < 12; p++) {
      const int s = h * 12 + p;
      const f32x4 wv = *(const f32x4*)(&tw[ql][s][0]);
      const int4 iv = *(const int4*)(&ti[ql][s][0]);
#pragma unroll
      for (int k = 0; k < 4; k++) {
        const int idx = (k == 0) ? iv.x : (k == 1) ? iv.y : (k == 2) ? iv.z : iv.w;
        const float w = wv[k];
        const ushort4 u = *(const ushort4*)(vb + (size_t)idx * 256);
        a0 += w * bf2f(u.x);
        a1 += w * bf2f(u.y);
        a2 += w * bf2f(u.z);
        a3 += w * bf2f(u.w);
      }
    }
    ushort4 o;
    o.x = f2bf(a0); o.y = f2bf(a1); o.z = f2bf(a2); o.w = f2bf(a3);
    *(ushort4*)(sampled + (size_t)bq * 256 + coff) = o;
  }
}

// ---------------- host launch ----------------
extern "C" void kernel_launch(void* const* d_in, const int* in_sizes, int n_in,
                              void* d_out, int out_size, void* d_ws, size_t ws_size,
                              hipStream_t stream) {
  const float* query      = (const float*)d_in[0];
  const float* refp       = (const float*)d_in[1];
  const float* value_flat = (const float*)d_in[2];
  const float* W_val      = (const float*)d_in[3];
  const float* b_val      = (const float*)d_in[4];
  const float* W_off      = (const float*)d_in[5];
  const float* b_off      = (const float*)d_in[6];
  const float* W_attn     = (const float*)d_in[7];
  const float* b_attn     = (const float*)d_in[8];
  const float* W_out      = (const float*)d_in[9];
  const float* b_out      = (const float*)d_in[10];

  char* w = (char*)d_ws;
  size_t o = 0;
  auto carve = [&](size_t bytes) -> void* {
    void* p = (void*)(w + o);
    o += (bytes + 255) & ~(size_t)255;
    return p;
  };
  unsigned short* q_bf    = (unsigned short*)carve((size_t)MTOT * 256 * 2);
  unsigned short* v_bf    = (unsigned short*)carve((size_t)MTOT * 256 * 2);
  unsigned short* Wval_t  = (unsigned short*)carve(256 * 256 * 2);
  unsigned short* Wcat_t  = (unsigned short*)carve(288 * 256 * 2);
  unsigned short* Wout_t  = (unsigned short*)carve(256 * 256 * 2);
  float*          bcat    = (float*)carve(288 * 4);
  unsigned short* value16 = (unsigned short*)carve((size_t)MTOT * 256 * 2);
  float*          logits  = (float*)carve((size_t)MTOT * 288 * 4);
  unsigned short* samp_bf = (unsigned short*)carve((size_t)MTOT * 256 * 2);

  const int n4 = MTOT * 256 / 4;
  const int cgrid = (n4 + 255) / 256;
  cast4_kernel<<<cgrid, 256, 0, stream>>>(query, q_bf, n4);
  cast4_kernel<<<cgrid, 256, 0, stream>>>(value_flat, v_bf, n4);
  prep_weights<<<288, 256, 0, stream>>>(W_val, W_off, W_attn, W_out, b_off, b_attn,
                                        Wval_t, Wcat_t, Wout_t, bcat);

  const int mg = (MTOT + 63) / 64;               // 348
  dim3 g1(mg, 4);
  gemm_bf16_64x64<true><<<g1, 256, 0, stream>>>(v_bf, Wval_t, b_val, value16, MTOT, 256);
  dim3 g2(mg, 5);
  gemm_bf16_64x64<false><<<g2, 256, 0, stream>>>(q_bf, Wcat_t, bcat, logits, MTOT, 288);

  const int sgrid = (MTOT + 3) / 4;              // 5555
  msda_sample2<<<sgrid, 256, 0, stream>>>(value16, logits, refp, samp_bf);

  dim3 g3(mg, 4);
  gemm_bf16_64x64<false><<<g3, 256, 0, stream>>>(samp_bf, Wout_t, b_out, (float*)d_out, MTOT, 256);
}

// Round 3
// 194.968 us; speedup vs baseline: 1.7603x; 1.0339x over previous
//
#include <hip/hip_runtime.h>

// MSDeformAttn: B=2, LQ=LV=11109, D=256, NH=8, HD=32, NL=3, NP=4
// shapes: (92,92),(46,46),(23,23); starts: 0, 8464, 10580
#define LQn   11109
#define Bn    2
#define MTOT  (Bn * LQn)   // 22218

typedef __attribute__((ext_vector_type(8))) short short8;
typedef __attribute__((ext_vector_type(4))) float f32x4;

__device__ __forceinline__ unsigned short f2bf(float f) {
  union { float f; unsigned int u; } v; v.f = f;
  unsigned int r = v.u + 0x7fffu + ((v.u >> 16) & 1u);  // RNE
  return (unsigned short)(r >> 16);
}

// ---------------- weight prep: transpose to (N x K) bf16, concat biases ----------------
__global__ __launch_bounds__(256) void prep_weights(
    const float* __restrict__ Wval, const float* __restrict__ Woff,
    const float* __restrict__ Wattn, const float* __restrict__ Wout,
    const float* __restrict__ boff, const float* __restrict__ battn,
    unsigned short* __restrict__ Wval_t, unsigned short* __restrict__ Wcat_t,
    unsigned short* __restrict__ Wout_t, float* __restrict__ bcat) {
  int i = blockIdx.x * 256 + threadIdx.x;   // grid = 288 blocks -> i < 73728
  int n = i >> 8, k = i & 255;              // Wt[n][k] = W[k][n]
  if (n < 256) {
    Wval_t[i] = f2bf(Wval[k * 256 + n]);
    Wout_t[i] = f2bf(Wout[k * 256 + n]);
  }
  float src = (n < 192) ? Woff[k * 192 + n] : Wattn[k * 96 + (n - 192)];
  Wcat_t[i] = f2bf(src);
  if (i < 288) bcat[i] = (i < 192) ? boff[i] : battn[i - 192];
}

// ---------------- fused GEMM1+GEMM2 (A fp32, converted in staging) ----------------
// grid = (348, 9): bn<4 -> value proj (N=256, bf16 head-major out)
//                  bn>=4 -> logits proj (N=288, fp32 out)
__global__ __launch_bounds__(256) void gemm_fused12(
    const float* __restrict__ Aval,           // (M,256) fp32
    const float* __restrict__ Aq,             // (M,256) fp32
    const unsigned short* __restrict__ Bval,  // (256,256) bf16 N-major
    const unsigned short* __restrict__ Bcat,  // (288,256) bf16 N-major
    const float* __restrict__ bval, const float* __restrict__ bcat,
    unsigned short* __restrict__ value16,     // [b][h][pix][32] bf16
    float* __restrict__ logits) {             // (M,288) fp32
  __shared__ unsigned short As[64][40];
  __shared__ unsigned short Bs[64][40];

  const int bm = blockIdx.x;
  int bn = blockIdx.y;
  const bool is2 = bn >= 4;
  if (is2) bn -= 4;
  const float* __restrict__ A = is2 ? Aq : Aval;
  const unsigned short* __restrict__ Bt = is2 ? Bcat : Bval;
  const float* __restrict__ bias = is2 ? bcat : bval;
  const int N = is2 ? 288 : 256;

  const int t = threadIdx.x;
  const int wave = t >> 6, lane = t & 63;
  const int wm = wave >> 1, wn = wave & 1;
  const int quad = lane >> 4, l16 = lane & 15;

  const int ldr = t >> 2;
  const int ldk = (t & 3) * 8;
  const int arow = bm * 64 + ldr;
  const int brow = bn * 64 + ldr;

  f32x4 acc[2][2];
  for (int i = 0; i < 2; i++)
    for (int j = 0; j < 2; j++) acc[i][j] = (f32x4){0.f, 0.f, 0.f, 0.f};

  for (int kb = 0; kb < 8; kb++) {
    const int k0 = kb * 32;
    float4 a0 = {0.f, 0.f, 0.f, 0.f}, a1 = a0;
    uint4 bv = {0u, 0u, 0u, 0u};
    if (arow < MTOT) {
      a0 = *(const float4*)(A + (size_t)arow * 256 + k0 + ldk);
      a1 = *(const float4*)(A + (size_t)arow * 256 + k0 + ldk + 4);
    }
    if (brow < N) bv = *(const uint4*)(Bt + (size_t)brow * 256 + k0 + ldk);
    ushort4 lo, hi;
    lo.x = f2bf(a0.x); lo.y = f2bf(a0.y); lo.z = f2bf(a0.z); lo.w = f2bf(a0.w);
    hi.x = f2bf(a1.x); hi.y = f2bf(a1.y); hi.z = f2bf(a1.z); hi.w = f2bf(a1.w);
    __syncthreads();
    *(ushort4*)(&As[ldr][ldk]) = lo;
    *(ushort4*)(&As[ldr][ldk + 4]) = hi;
    *(uint4*)(&Bs[ldr][ldk]) = bv;
    __syncthreads();
    short8 af[2], bfr[2];
    for (int i = 0; i < 2; i++)
      af[i] = *(const short8*)(&As[wm * 32 + i * 16 + l16][quad * 8]);
    for (int j = 0; j < 2; j++)
      bfr[j] = *(const short8*)(&Bs[wn * 32 + j * 16 + l16][quad * 8]);
    for (int i = 0; i < 2; i++)
      for (int j = 0; j < 2; j++)
        acc[i][j] = __builtin_amdgcn_mfma_f32_16x16x32_bf16(af[i], bfr[j], acc[i][j], 0, 0, 0);
  }

  for (int i = 0; i < 2; i++)
    for (int j = 0; j < 2; j++) {
      int colg = bn * 64 + wn * 32 + j * 16 + l16;
      if (colg >= N) continue;
      float bsv = bias[colg];
      int row0 = bm * 64 + wm * 32 + i * 16 + quad * 4;
      for (int r = 0; r < 4; r++) {
        int rg = row0 + r;
        if (rg >= MTOT) continue;
        float v = acc[i][j][r] + bsv;
        if (is2) {
          logits[(size_t)rg * 288 + colg] = v;
        } else {
          int b = (rg >= LQn) ? 1 : 0;
          int p = rg - b * LQn;
          value16[((size_t)(b * 8 + (colg >> 5)) * LQn + p) * 32 + (colg & 31)] = f2bf(v);
        }
      }
    }
}

// ---------------- GEMM3: A bf16, out fp32 (out proj) ----------------
__global__ __launch_bounds__(256) void gemm_a16(
    const unsigned short* __restrict__ A,   // (M,256) bf16
    const unsigned short* __restrict__ Bt,  // (256,256) bf16 N-major
    const float* __restrict__ bias,
    float* __restrict__ C) {                // (M,256) fp32
  __shared__ unsigned short As[64][40];
  __shared__ unsigned short Bs[64][40];

  const int t = threadIdx.x;
  const int bm = blockIdx.x, bn = blockIdx.y;
  const int wave = t >> 6, lane = t & 63;
  const int wm = wave >> 1, wn = wave & 1;
  const int quad = lane >> 4, l16 = lane & 15;

  const int ldr = t >> 2;
  const int ldk = (t & 3) * 8;
  const int arow = bm * 64 + ldr;
  const int brow = bn * 64 + ldr;

  f32x4 acc[2][2];
  for (int i = 0; i < 2; i++)
    for (int j = 0; j < 2; j++) acc[i][j] = (f32x4){0.f, 0.f, 0.f, 0.f};

  for (int kb = 0; kb < 8; kb++) {
    const int k0 = kb * 32;
    uint4 av = {0u, 0u, 0u, 0u}, bv = {0u, 0u, 0u, 0u};
    if (arow < MTOT) av = *(const uint4*)(A + (size_t)arow * 256 + k0 + ldk);
    bv = *(const uint4*)(Bt + (size_t)brow * 256 + k0 + ldk);
    __syncthreads();
    *(uint4*)(&As[ldr][ldk]) = av;
    *(uint4*)(&Bs[ldr][ldk]) = bv;
    __syncthreads();
    short8 af[2], bfr[2];
    for (int i = 0; i < 2; i++)
      af[i] = *(const short8*)(&As[wm * 32 + i * 16 + l16][quad * 8]);
    for (int j = 0; j < 2; j++)
      bfr[j] = *(const short8*)(&Bs[wn * 32 + j * 16 + l16][quad * 8]);
    for (int i = 0; i < 2; i++)
      for (int j = 0; j < 2; j++)
        acc[i][j] = __builtin_amdgcn_mfma_f32_16x16x32_bf16(af[i], bfr[j], acc[i][j], 0, 0, 0);
  }

  for (int i = 0; i < 2; i++)
    for (int j = 0; j < 2; j++) {
      int colg = bn * 64 + wn * 32 + j * 16 + l16;
      float bsv = bias[colg];
      int row0 = bm * 64 + wm * 32 + i * 16 + quad * 4;
      for (int r = 0; r < 4; r++) {
        int rg = row0 + r;
        if (rg < MTOT) C[(size_t)rg * 256 + colg] = acc[i][j][r] + bsv;
      }
    }
}

// ---------------- sampling + softmax + weighted sum, v3 ----------------
// 1 wave/query, 4 queries/block. Phase 1a: 8 lanes/query compute per-head
// softmax max & 1/den. Phase 1b: 96 slots build premultiplied corner weights
// + byte offsets. Phase 2: lane=(h=lane>>3, cg=lane&7), 4 ch/lane, value in
// head-major layout [b][h][pix][32].
__global__ __launch_bounds__(256) void msda_sample3(
    const unsigned short* __restrict__ value16,  // [b][h][pix][32] bf16
    const float* __restrict__ logits,            // (M,288)
    const float* __restrict__ refp,              // (M,3,2) (y,x)
    unsigned short* __restrict__ sampled) {      // (M,256) bf16
  __shared__ float lg[4][288];
  __shared__ float rfs[4][6];
  __shared__ float hmx[4][8], hrd[4][8];
  __shared__ float tw[4][96][4];
  __shared__ unsigned int ti[4][96][4];   // pix*64 byte offsets

  const int t = threadIdx.x;
  const int ql = t >> 6;
  const int lane = t & 63;
  const int bq = blockIdx.x * 4 + ql;
  const bool qv = bq < MTOT;

  if (qv) {
    for (int i = lane; i < 288; i += 64) lg[ql][i] = logits[(size_t)bq * 288 + i];
    if (lane < 6) rfs[ql][lane] = refp[(size_t)bq * 6 + lane];
  }
  __syncthreads();

  if (qv && lane < 8) {
    float mx = -1e30f;
#pragma unroll
    for (int i = 0; i < 12; i++) mx = fmaxf(mx, lg[ql][192 + lane * 12 + i]);
    float den = 0.f;
#pragma unroll
    for (int i = 0; i < 12; i++) den += __expf(lg[ql][192 + lane * 12 + i] - mx);
    hmx[ql][lane] = mx;
    hrd[ql][lane] = 1.0f / den;
  }
  __syncthreads();

  if (qv) {
    const int Hs[3] = {92, 46, 23};
    const int Ss[3] = {0, 8464, 10580};
#pragma unroll
    for (int rnd = 0; rnd < 2; rnd++) {
      const int s = lane + rnd * 64;
      if (s < 96) {
        const int h = s / 12;
        const int pl = s - h * 12;
        const int l = pl >> 2;
        const int H = Hs[l], W = Hs[l], S = Ss[l];
        const float aw = __expf(lg[ql][192 + s] - hmx[ql][h]) * hrd[ql][h];
        const float offy = lg[ql][2 * s], offx = lg[ql][2 * s + 1];
        const float x = rfs[ql][l * 2 + 1] * W + offx - 0.5f;
        const float y = rfs[ql][l * 2 + 0] * H + offy - 0.5f;
        const float xf = floorf(x), yf = floorf(y);
        const int x0 = (int)xf, y0 = (int)yf;
        const float lx = x - xf, ly = y - yf;
        const bool xv0 = (x0 >= 0) & (x0 < W), xv1 = (x0 + 1 >= 0) & (x0 + 1 < W);
        const bool yv0 = (y0 >= 0) & (y0 < H), yv1 = (y0 + 1 >= 0) & (y0 + 1 < H);
        const int xc0 = min(max(x0, 0), W - 1), xc1 = min(max(x0 + 1, 0), W - 1);
        const int yc0 = min(max(y0, 0), H - 1), yc1 = min(max(y0 + 1, 0), H - 1);
        ti[ql][s][0] = (unsigned)(S + yc0 * W + xc0) << 6;
        ti[ql][s][1] = (unsigned)(S + yc0 * W + xc1) << 6;
        ti[ql][s][2] = (unsigned)(S + yc1 * W + xc0) << 6;
        ti[ql][s][3] = (unsigned)(S + yc1 * W + xc1) << 6;
        tw[ql][s][0] = (yv0 & xv0) ? aw * (1.f - ly) * (1.f - lx) : 0.f;
        tw[ql][s][1] = (yv0 & xv1) ? aw * (1.f - ly) * lx : 0.f;
        tw[ql][s][2] = (yv1 & xv0) ? aw * ly * (1.f - lx) : 0.f;
        tw[ql][s][3] = (yv1 & xv1) ? aw * ly * lx : 0.f;
      }
    }
  }
  __syncthreads();

  if (qv) {
    const int h = lane >> 3, cg = lane & 7;
    const unsigned laneoff = (unsigned)h * (LQn * 64u) + (unsigned)cg * 8u;
    const char* __restrict__ vb =
        (const char*)(value16 + (size_t)(bq / LQn) * (8u * LQn * 32u));
    float a0 = 0.f, a1 = 0.f, a2 = 0.f, a3 = 0.f;
#pragma unroll
    for (int p = 0; p < 12; p++) {
      const int s = h * 12 + p;
      const f32x4 wv = *(const f32x4*)(&tw[ql][s][0]);
      const uint4 iv = *(const uint4*)(&ti[ql][s][0]);
#pragma unroll
      for (int k = 0; k < 4; k++) {
        const unsigned tib = (k == 0) ? iv.x : (k == 1) ? iv.y : (k == 2) ? iv.z : iv.w;
        const float w = wv[k];
        const uint2 u = *(const uint2*)(vb + (laneoff + tib));
        a0 += w * __uint_as_float(u.x << 16);
        a1 += w * __uint_as_float(u.x & 0xffff0000u);
        a2 += w * __uint_as_float(u.y << 16);
        a3 += w * __uint_as_float(u.y & 0xffff0000u);
      }
    }
    ushort4 o;
    o.x = f2bf(a0); o.y = f2bf(a1); o.z = f2bf(a2); o.w = f2bf(a3);
    *(ushort4*)(sampled + (size_t)bq * 256 + h * 32 + cg * 4) = o;
  }
}

// ---------------- host launch ----------------
extern "C" void kernel_launch(void* const* d_in, const int* in_sizes, int n_in,
                              void* d_out, int out_size, void* d_ws, size_t ws_size,
                              hipStream_t stream) {
  const float* query      = (const float*)d_in[0];
  const float* refp       = (const float*)d_in[1];
  const float* value_flat = (const float*)d_in[2];
  const float* W_val      = (const float*)d_in[3];
  const float* b_val      = (const float*)d_in[4];
  const float* W_off      = (const float*)d_in[5];
  const float* b_off      = (const float*)d_in[6];
  const float* W_attn     = (const float*)d_in[7];
  const float* b_attn     = (const float*)d_in[8];
  const float* W_out      = (const float*)d_in[9];
  const float* b_out      = (const float*)d_in[10];

  char* w = (char*)d_ws;
  size_t o = 0;
  auto carve = [&](size_t bytes) -> void* {
    void* p = (void*)(w + o);
    o += (bytes + 255) & ~(size_t)255;
    return p;
  };
  unsigned short* Wval_t  = (unsigned short*)carve(256 * 256 * 2);
  unsigned short* Wcat_t  = (unsigned short*)carve(288 * 256 * 2);
  unsigned short* Wout_t  = (unsigned short*)carve(256 * 256 * 2);
  float*          bcat    = (float*)carve(288 * 4);
  unsigned short* value16 = (unsigned short*)carve((size_t)MTOT * 256 * 2);
  float*          logits  = (float*)carve((size_t)MTOT * 288 * 4);
  unsigned short* samp_bf = (unsigned short*)carve((size_t)MTOT * 256 * 2);

  prep_weights<<<288, 256, 0, stream>>>(W_val, W_off, W_attn, W_out, b_off, b_attn,
                                        Wval_t, Wcat_t, Wout_t, bcat);

  const int mg = (MTOT + 63) / 64;               // 348
  dim3 g12(mg, 9);                               // 4 value-proj tiles + 5 logits tiles
  gemm_fused12<<<g12, 256, 0, stream>>>(value_flat, query, Wval_t, Wcat_t,
                                        b_val, bcat, value16, logits);

  const int sgrid = (MTOT + 3) / 4;              // 5555
  msda_sample3<<<sgrid, 256, 0, stream>>>(value16, logits, refp, samp_bf);

  dim3 g3(mg, 4);
  gemm_a16<<<g3, 256, 0, stream>>>(samp_bf, Wout_t, b_out, (float*)d_out);
}